// Round 8
// baseline (895.947 us; speedup 1.0000x reference)
//
#include <hip/hip_runtime.h>
#include <cstddef>

#define CUR_ELEMS (25600 * 256)   // [50*512][256] f32 scratch (cur, then ff0 in place)
#define WROWS 65792               // 257 rows * 256 (row 256 = zeros for list padding)

// ---------------------------------------------------------------------------
// K0: one-time weight transposes into workspace (k-major for coalesced row
// gathers), each with an extra all-zero row at index 256 (list-padding sink).
// ---------------------------------------------------------------------------
__global__ __launch_bounds__(256) void k0_transpose(
    const float* __restrict__ Wf, const float* __restrict__ Wr,
    const float* __restrict__ Wo, float* __restrict__ ws) {
  int tid = blockIdx.x * blockDim.x + threadIdx.x;
  float* Wr0T = ws + CUR_ELEMS;
  float* Wf1T = Wr0T + WROWS;
  float* Wr1T = Wf1T + WROWS;
  float* WoT  = Wr1T + WROWS;
  if (tid < WROWS) {
    int k = tid >> 8, h = tid & 255;
    Wr0T[tid] = (k < 256) ? Wr[h * 256 + k] : 0.f;
  } else if (tid < 2 * WROWS) {
    int i = tid - WROWS; int k = i >> 8, h = i & 255;
    Wf1T[i] = (k < 256) ? Wf[65536 + h * 256 + k] : 0.f;
  } else if (tid < 3 * WROWS) {
    int i = tid - 2 * WROWS; int k = i >> 8, h = i & 255;
    Wr1T[i] = (k < 256) ? Wr[65536 + h * 256 + k] : 0.f;
  } else if (tid < 3 * WROWS + 5140) {
    int i = tid - 3 * WROWS; int k = i / 20, j = i - k * 20;
    WoT[i] = (k < 256) ? Wo[j * 256 + k] : 0.f;
  }
}

// ---------------------------------------------------------------------------
// K1: cur[t][b][h] = sum_i x[b, t-d_i, :] . Wd[i][h][:]  + sum_i bd[i][h]
// 128x128 tile, 8x8 micro-tile, double-buffered LDS, 2-ahead reg prefetch.
// (unchanged from round 6)
// ---------------------------------------------------------------------------
__global__ __launch_bounds__(256) void k1_cur(
    const float* __restrict__ x, const float* __restrict__ Wd,
    const float* __restrict__ bd, float* __restrict__ cur) {
  __shared__ float As[2][16][132];
  __shared__ float Bs[2][16][132];
  const int t  = 49 - blockIdx.y;              // heavy (3-pass) blocks first
  const int bt = blockIdx.x >> 1, ht = blockIdx.x & 1;
  const int b0 = bt * 128, h0 = ht * 128;
  const int tid = threadIdx.x;
  const int tx = tid & 15, ty = tid >> 4;
  const int r = tid & 127, half = tid >> 7;
  const int kk0a = half * 8;

  float acc[8][8];
#pragma unroll
  for (int i = 0; i < 8; ++i)
#pragma unroll
    for (int j = 0; j < 8; ++j) acc[i][j] = 0.f;

  const int DEL[3] = {0, 16, 32};
#pragma unroll 1
  for (int di = 0; di < 3; ++di) {
    const int d = DEL[di];
    if (t < d) continue;
    const int tsrc = t - d;
    const float* Arow = x + ((size_t)(b0 + r) * 50 + tsrc) * 700;
    const float* Brow = Wd + (size_t)di * 179200 + (size_t)(h0 + r) * 700;
    float4 pa0, pa1, pb0, pb1;
    pa0 = *(const float4*)(Arow + kk0a);
    pa1 = *(const float4*)(Arow + kk0a + 4);
    pb0 = *(const float4*)(Brow + kk0a);
    pb1 = *(const float4*)(Brow + kk0a + 4);
    As[0][kk0a + 0][r] = pa0.x; As[0][kk0a + 1][r] = pa0.y;
    As[0][kk0a + 2][r] = pa0.z; As[0][kk0a + 3][r] = pa0.w;
    As[0][kk0a + 4][r] = pa1.x; As[0][kk0a + 5][r] = pa1.y;
    As[0][kk0a + 6][r] = pa1.z; As[0][kk0a + 7][r] = pa1.w;
    Bs[0][kk0a + 0][r] = pb0.x; Bs[0][kk0a + 1][r] = pb0.y;
    Bs[0][kk0a + 2][r] = pb0.z; Bs[0][kk0a + 3][r] = pb0.w;
    Bs[0][kk0a + 4][r] = pb1.x; Bs[0][kk0a + 5][r] = pb1.y;
    Bs[0][kk0a + 6][r] = pb1.z; Bs[0][kk0a + 7][r] = pb1.w;
    pa0 = *(const float4*)(Arow + 16 + kk0a);
    pa1 = *(const float4*)(Arow + 16 + kk0a + 4);
    pb0 = *(const float4*)(Brow + 16 + kk0a);
    pb1 = *(const float4*)(Brow + 16 + kk0a + 4);
    __syncthreads();
#pragma unroll 1
    for (int c = 0; c < 44; ++c) {
      const int cb = c & 1, nb = cb ^ 1;
      if (c < 43) {
        As[nb][kk0a + 0][r] = pa0.x; As[nb][kk0a + 1][r] = pa0.y;
        As[nb][kk0a + 2][r] = pa0.z; As[nb][kk0a + 3][r] = pa0.w;
        As[nb][kk0a + 4][r] = pa1.x; As[nb][kk0a + 5][r] = pa1.y;
        As[nb][kk0a + 6][r] = pa1.z; As[nb][kk0a + 7][r] = pa1.w;
        Bs[nb][kk0a + 0][r] = pb0.x; Bs[nb][kk0a + 1][r] = pb0.y;
        Bs[nb][kk0a + 2][r] = pb0.z; Bs[nb][kk0a + 3][r] = pb0.w;
        Bs[nb][kk0a + 4][r] = pb1.x; Bs[nb][kk0a + 5][r] = pb1.y;
        Bs[nb][kk0a + 6][r] = pb1.z; Bs[nb][kk0a + 7][r] = pb1.w;
      }
      if (c < 42) {
        const int i0 = (c + 2) * 16 + kk0a, i1 = i0 + 4;
        pa0 = (i0 + 3 < 700) ? *(const float4*)(Arow + i0)
                             : make_float4(0.f, 0.f, 0.f, 0.f);
        pa1 = (i1 + 3 < 700) ? *(const float4*)(Arow + i1)
                             : make_float4(0.f, 0.f, 0.f, 0.f);
        pb0 = (i0 + 3 < 700) ? *(const float4*)(Brow + i0)
                             : make_float4(0.f, 0.f, 0.f, 0.f);
        pb1 = (i1 + 3 < 700) ? *(const float4*)(Brow + i1)
                             : make_float4(0.f, 0.f, 0.f, 0.f);
      }
#pragma unroll
      for (int kk = 0; kk < 16; ++kk) {
        const float4 a0 = *(const float4*)&As[cb][kk][ty * 4];
        const float4 a1 = *(const float4*)&As[cb][kk][64 + ty * 4];
        const float4 c0 = *(const float4*)&Bs[cb][kk][tx * 4];
        const float4 c1 = *(const float4*)&Bs[cb][kk][64 + tx * 4];
        const float ar[8] = {a0.x, a0.y, a0.z, a0.w, a1.x, a1.y, a1.z, a1.w};
        const float br[8] = {c0.x, c0.y, c0.z, c0.w, c1.x, c1.y, c1.z, c1.w};
#pragma unroll
        for (int rr = 0; rr < 8; ++rr)
#pragma unroll
          for (int cc = 0; cc < 8; ++cc) acc[rr][cc] += ar[rr] * br[cc];
      }
      __syncthreads();
    }
  }
  float bias[8];
#pragma unroll
  for (int q = 0; q < 2; ++q)
#pragma unroll
    for (int c = 0; c < 4; ++c) {
      const int col = h0 + q * 64 + tx * 4 + c;
      bias[q * 4 + c] = bd[col] + bd[256 + col] + bd[512 + col];
    }
#pragma unroll
  for (int p = 0; p < 2; ++p)
#pragma unroll
    for (int rr = 0; rr < 4; ++rr) {
      const int row = b0 + p * 64 + ty * 4 + rr;
      float* dst = cur + ((size_t)t * 512 + row) * 256 + h0;
      const int ai = p * 4 + rr;
      float4 v0 = make_float4(acc[ai][0] + bias[0], acc[ai][1] + bias[1],
                              acc[ai][2] + bias[2], acc[ai][3] + bias[3]);
      float4 v1 = make_float4(acc[ai][4] + bias[4], acc[ai][5] + bias[5],
                              acc[ai][6] + bias[6], acc[ai][7] + bias[7]);
      *(float4*)(dst + tx * 4) = v0;
      *(float4*)(dst + 64 + tx * 4) = v1;
    }
}

// ---------------------------------------------------------------------------
// K1b: ff0[m][h] = cur[m][:] . Wf0[h][:] + bf0[h], IN PLACE over cur.
// ---------------------------------------------------------------------------
__global__ __launch_bounds__(256) void k1b_ff0(
    const float* __restrict__ Wf, const float* __restrict__ bf,
    float* __restrict__ cur) {
  __shared__ float As[16][68];
  __shared__ float Bs[16][260];
  const int m0 = blockIdx.x * 64;
  const int tid = threadIdx.x;
  const int tx = tid & 15, ty = tid >> 4;
  const int lr = tid & 63, akk = (tid >> 6) * 4;

  float acc[4][16];
#pragma unroll
  for (int i = 0; i < 4; ++i)
#pragma unroll
    for (int j = 0; j < 16; ++j) acc[i][j] = 0.f;

#pragma unroll 1
  for (int k0 = 0; k0 < 256; k0 += 16) {
    float4 av = *(const float4*)(cur + (size_t)(m0 + lr) * 256 + k0 + akk);
    As[akk + 0][lr] = av.x; As[akk + 1][lr] = av.y;
    As[akk + 2][lr] = av.z; As[akk + 3][lr] = av.w;
#pragma unroll
    for (int e = 0; e < 4; ++e) {
      const int hh = e * 64 + lr;
      float4 bv = *(const float4*)(Wf + (size_t)hh * 256 + k0 + akk);
      Bs[akk + 0][hh] = bv.x; Bs[akk + 1][hh] = bv.y;
      Bs[akk + 2][hh] = bv.z; Bs[akk + 3][hh] = bv.w;
    }
    __syncthreads();
#pragma unroll
    for (int kk = 0; kk < 16; ++kk) {
      const float4 a = *(const float4*)&As[kk][ty * 4];
      const float ar[4] = {a.x, a.y, a.z, a.w};
#pragma unroll
      for (int q = 0; q < 4; ++q) {
        const float4 bq = *(const float4*)&Bs[kk][q * 64 + tx * 4];
        const float br[4] = {bq.x, bq.y, bq.z, bq.w};
#pragma unroll
        for (int rr = 0; rr < 4; ++rr)
#pragma unroll
          for (int cc = 0; cc < 4; ++cc)
            acc[rr][q * 4 + cc] += ar[rr] * br[cc];
      }
    }
    __syncthreads();
  }
  float bias[16];
#pragma unroll
  for (int q = 0; q < 4; ++q)
#pragma unroll
    for (int c = 0; c < 4; ++c) bias[q * 4 + c] = bf[q * 64 + tx * 4 + c];
#pragma unroll
  for (int rr = 0; rr < 4; ++rr) {
    float* dst = cur + (size_t)(m0 + ty * 4 + rr) * 256;
#pragma unroll
    for (int q = 0; q < 4; ++q) {
      float4 v = make_float4(acc[rr][q * 4 + 0] + bias[q * 4 + 0],
                             acc[rr][q * 4 + 1] + bias[q * 4 + 1],
                             acc[rr][q * 4 + 2] + bias[q * 4 + 2],
                             acc[rr][q * 4 + 3] + bias[q * 4 + 3]);
      *(float4*)(dst + q * 64 + tx * 4) = v;
    }
  }
}

// ---------------------------------------------------------------------------
// K2 helpers. One wave per batch row; lane owns h = lane*4..+3. Weight row =
// one coalesced 1KB wave load (float4/lane). Lists: pre-scaled offsets
// (k<<8), padded to a MULTIPLE OF 32 rows with the zero-row sink -> the
// gather runs a DEPTH-4 rotating pipeline (32 loads in flight, oldest group
// summed while 3 newer groups fly).
// ---------------------------------------------------------------------------
__device__ __forceinline__ void load8rows(const float* __restrict__ W,
                                          const int* LC, int j, int l4,
                                          float4* w) {
  const int4 a = *(const int4*)(LC + j);
  const int4 c = *(const int4*)(LC + j + 4);
  w[0] = *(const float4*)(W + a.x + l4);
  w[1] = *(const float4*)(W + a.y + l4);
  w[2] = *(const float4*)(W + a.z + l4);
  w[3] = *(const float4*)(W + a.w + l4);
  w[4] = *(const float4*)(W + c.x + l4);
  w[5] = *(const float4*)(W + c.y + l4);
  w[6] = *(const float4*)(W + c.z + l4);
  w[7] = *(const float4*)(W + c.w + l4);
}

__device__ __forceinline__ void add8rows(float4& acc, const float4* w) {
  float4 t0, t1, t2, t3;
  t0.x = w[0].x + w[1].x; t0.y = w[0].y + w[1].y; t0.z = w[0].z + w[1].z; t0.w = w[0].w + w[1].w;
  t1.x = w[2].x + w[3].x; t1.y = w[2].y + w[3].y; t1.z = w[2].z + w[3].z; t1.w = w[2].w + w[3].w;
  t2.x = w[4].x + w[5].x; t2.y = w[4].y + w[5].y; t2.z = w[4].z + w[5].z; t2.w = w[4].w + w[5].w;
  t3.x = w[6].x + w[7].x; t3.y = w[6].y + w[7].y; t3.z = w[6].z + w[7].z; t3.w = w[6].w + w[7].w;
  t0.x += t1.x; t0.y += t1.y; t0.z += t1.z; t0.w += t1.w;
  t2.x += t3.x; t2.y += t3.y; t2.z += t3.z; t2.w += t3.w;
  acc.x += t0.x + t2.x; acc.y += t0.y + t2.y;
  acc.z += t0.z + t2.z; acc.w += t0.w + t2.w;
}

__device__ __forceinline__ float4 gather_rows(const float* __restrict__ W,
                                              const int* LC, int n, int l4) {
  float4 acc = make_float4(0.f, 0.f, 0.f, 0.f);
  const int G = n >> 3;   // n is a multiple of 32 -> G multiple of 4
  if (G == 0) return acc;
  float4 w0[8], w1[8], w2[8], w3[8];
  load8rows(W, LC, 0,  l4, w0);
  load8rows(W, LC, 8,  l4, w1);
  load8rows(W, LC, 16, l4, w2);
  load8rows(W, LC, 24, l4, w3);
  int g = 4;
  for (; g + 4 <= G; g += 4) {
    add8rows(acc, w0); load8rows(W, LC, (g + 0) * 8, l4, w0);
    add8rows(acc, w1); load8rows(W, LC, (g + 1) * 8, l4, w1);
    add8rows(acc, w2); load8rows(W, LC, (g + 2) * 8, l4, w2);
    add8rows(acc, w3); load8rows(W, LC, (g + 3) * 8, l4, w3);
  }
  add8rows(acc, w0); add8rows(acc, w1);
  add8rows(acc, w2); add8rows(acc, w3);
  return acc;
}

__device__ __forceinline__ float add8o(const float* w) {
  return ((w[0] + w[1]) + (w[2] + w[3])) + ((w[4] + w[5]) + (w[6] + w[7]));
}

// ---------------------------------------------------------------------------
// K2: 50-step recurrent scan. ONE WAVE per batch row (512 blocks x 64 thr),
// zero barriers. Readout: WoT in LDS; 60 lanes, 3 per class, two-shuffle
// reduce. __launch_bounds__(64, 1): only 2 waves/CU can ever be resident
// (512 waves / 256 CUs), so let the allocator use up to 512 VGPRs — R6's
// (64) default forced 112 VGPRs and collapsed the depth-4 pipeline (needs
// 128 VGPRs of load buffers alone).
// ---------------------------------------------------------------------------
__global__ __launch_bounds__(64, 1) void k2_scan(
    const float* __restrict__ ff0, const float* __restrict__ Wr0T,
    const float* __restrict__ Wf1T, const float* __restrict__ Wr1T,
    const float* __restrict__ WoT, const float* __restrict__ bf,
    const float* __restrict__ bo, float* __restrict__ out) {
  __shared__ __align__(16) int LC0[288];   // spk0 offsets (k<<8), %32-padded
  __shared__ __align__(16) int LC1[288];   // spk1 offsets (k<<8), %32-padded
  __shared__ __align__(16) int LCb[280];   // spk1 offsets (k*20), %24-padded
  __shared__ float WoTl[5140];             // 257 x 20 (row 256 = zeros)
  __shared__ float obuf[20];
  const int b = blockIdx.x;
  const int lane = threadIdx.x;
  const int l4 = lane * 4;
  const unsigned long long lb = (1ull << lane) - 1ull;

  // preload WoT -> LDS (one-time; 5140 = 1285 float4)
  for (int i = lane; i < 1285; i += 64)
    *(float4*)(WoTl + 4 * i) = *(const float4*)(WoT + 4 * i);

  float4 m0 = make_float4(0.f, 0.f, 0.f, 0.f), m1 = m0;
  float4 s0v = m0, s1v = m0;
  const float4 bf1v = *(const float4*)(bf + 256 + l4);
  float omem = 0.f, ospk = 0.f, osum = 0.f, omot = 0.f;
  const float bov = (lane < 20) ? bo[lane] : 0.f;
  const int ro = lane / 3, rc = lane - ro * 3;   // readout map (lanes 0..59)
  int n0 = 0, n1g = 0, n1r = 0;

  const float* ffp = ff0 + (size_t)b * 256 + l4;
  float4 ff = *(const float4*)ffp;

#pragma unroll 1
  for (int t = 0; t < 50; ++t) {
    float4 ffn = ff;
    if (t < 49) ffn = *(const float4*)(ffp + (size_t)(t + 1) * 131072);
    // ---- layer 0: recurrent gather over spk0(t-1)
    {
      const float4 g = gather_rows(Wr0T, LC0, n0, l4);
      m0.x = m0.x * 0.8f * (1.f - s0v.x) + ff.x + g.x;
      m0.y = m0.y * 0.8f * (1.f - s0v.y) + ff.y + g.y;
      m0.z = m0.z * 0.8f * (1.f - s0v.z) + ff.z + g.z;
      m0.w = m0.w * 0.8f * (1.f - s0v.w) + ff.w + g.w;
      s0v.x = (m0.x - 0.3f > 0.f) ? 1.f : 0.f;
      s0v.y = (m0.y - 0.3f > 0.f) ? 1.f : 0.f;
      s0v.z = (m0.z - 0.3f > 0.f) ? 1.f : 0.f;
      s0v.w = (m0.w - 0.3f > 0.f) ? 1.f : 0.f;
    }
    {  // compact spk0 -> LC0 (%32-pad with zero-row sink)
      const float sv[4] = {s0v.x, s0v.y, s0v.z, s0v.w};
      int base = 0;
#pragma unroll
      for (int q = 0; q < 4; ++q) {
        const bool sp = sv[q] > 0.f;
        const unsigned long long mk = __ballot(sp);
        const int pos = base + (int)__popcll(mk & lb);
        if (sp) LC0[pos] = (l4 + q) << 8;
        base += (int)__popcll(mk);
      }
      const int pad = (-base) & 31;
      if (lane < pad) LC0[base + lane] = 256 << 8;
      n0 = base + pad;
    }
    // ---- layer 1: Wf1 gather over spk0(t) + Wr1 gather over spk1(t-1)
    {
      const float4 g1 = gather_rows(Wf1T, LC0, n0, l4);
      const float4 g2 = gather_rows(Wr1T, LC1, n1g, l4);
      m1.x = m1.x * 0.8f * (1.f - s1v.x) + bf1v.x + g1.x + g2.x;
      m1.y = m1.y * 0.8f * (1.f - s1v.y) + bf1v.y + g1.y + g2.y;
      m1.z = m1.z * 0.8f * (1.f - s1v.z) + bf1v.z + g1.z + g2.z;
      m1.w = m1.w * 0.8f * (1.f - s1v.w) + bf1v.w + g1.w + g2.w;
      s1v.x = (m1.x - 0.3f > 0.f) ? 1.f : 0.f;
      s1v.y = (m1.y - 0.3f > 0.f) ? 1.f : 0.f;
      s1v.z = (m1.z - 0.3f > 0.f) ? 1.f : 0.f;
      s1v.w = (m1.w - 0.3f > 0.f) ? 1.f : 0.f;
    }
    {  // compact spk1 -> LC1 (%32, k<<8) and LCb (%24, k*20)
      const float sv[4] = {s1v.x, s1v.y, s1v.z, s1v.w};
      int base = 0;
#pragma unroll
      for (int q = 0; q < 4; ++q) {
        const bool sp = sv[q] > 0.f;
        const unsigned long long mk = __ballot(sp);
        const int pos = base + (int)__popcll(mk & lb);
        if (sp) { LC1[pos] = (l4 + q) << 8; LCb[pos] = (l4 + q) * 20; }
        base += (int)__popcll(mk);
      }
      const int padg = (-base) & 31;
      if (lane < padg) LC1[base + lane] = 256 << 8;
      n1g = base + padg;
      const int rem = base % 24;
      const int padr = rem ? (24 - rem) : 0;
      if (lane < padr) LCb[base + lane] = 256 * 20;
      n1r = base + padr;
    }
    // ---- readout: lanes 0..59, 3 lanes per class, stride-3 LDS gather
    {
      float v = 0.f;
      if (lane < 60) {
        const int GR = n1r / 24;   // per-lane groups of 8
        int j = rc;
        for (int g = 0; g < GR; ++g) {
          int idx[8]; float w[8];
#pragma unroll
          for (int u = 0; u < 8; ++u) idx[u] = LCb[j + 3 * u];
#pragma unroll
          for (int u = 0; u < 8; ++u) w[u] = WoTl[idx[u] + ro];
          v += add8o(w);
          j += 24;
        }
      }
      // 3-lane reduce: shuffle the ORIGINAL v twice (R3-corrected)
      const float v1 = __shfl_down(v, 1);
      const float v2 = __shfl_down(v, 2);
      v += v1 + v2;
      if (rc == 0 && lane < 60) obuf[ro] = v;  // same-wave LDS, in order
      if (lane < 20) {
        const float oacc = bov + obuf[lane];
        omem = omem * 0.8f * (1.f - ospk) + oacc;
        ospk = (omem - 0.3f > 0.f) ? 1.f : 0.f;
        osum += ospk;
        obuf[lane] = omem;
      }
      if (lane < 20) {  // stable softmax accumulate
        float ov[20];
#pragma unroll
        for (int j2 = 0; j2 < 20; ++j2) ov[j2] = obuf[j2];
        float mx = ov[0];
#pragma unroll
        for (int j2 = 1; j2 < 20; ++j2) mx = fmaxf(mx, ov[j2]);
        float sm = 0.f;
#pragma unroll
        for (int j2 = 0; j2 < 20; ++j2) sm += expf(ov[j2] - mx);
        omot += expf(omem - mx) / sm;
      }
    }
    ff = ffn;
  }
  if (lane < 20) {
    out[b * 20 + lane] = osum / 50.0f;
    out[10240 + b * 20 + lane] = omot;
  }
}

// ---------------------------------------------------------------------------
extern "C" void kernel_launch(void* const* d_in, const int* in_sizes, int n_in,
                              void* d_out, int out_size, void* d_ws, size_t ws_size,
                              hipStream_t stream) {
  const float* x  = (const float*)d_in[0];
  const float* Wd = (const float*)d_in[1];
  const float* bd = (const float*)d_in[2];
  const float* Wf = (const float*)d_in[3];
  const float* bf = (const float*)d_in[4];
  const float* Wr = (const float*)d_in[5];
  const float* Wo = (const float*)d_in[6];
  const float* bo = (const float*)d_in[7];
  float* out = (float*)d_out;
  float* ws  = (float*)d_ws;

  float* cur  = ws;                    // [25600][256], becomes ff0 in place
  float* Wr0T = ws + CUR_ELEMS;
  float* Wf1T = Wr0T + WROWS;
  float* Wr1T = Wf1T + WROWS;
  float* WoT  = Wr1T + WROWS;

  hipLaunchKernelGGL(k0_transpose, dim3(792), dim3(256), 0, stream, Wf, Wr, Wo, ws);
  hipLaunchKernelGGL(k1_cur, dim3(8, 50), dim3(256), 0, stream, x, Wd, bd, cur);
  hipLaunchKernelGGL(k1b_ff0, dim3(400), dim3(256), 0, stream, Wf, bf, cur);
  hipLaunchKernelGGL(k2_scan, dim3(512), dim3(64), 0, stream, cur, Wr0T, Wf1T,
                     Wr1T, WoT, bf, bo, out);
}

// Round 9
// 849.972 us; speedup vs baseline: 1.0541x; 1.0541x over previous
//
#include <hip/hip_runtime.h>
#include <cstddef>

#define CUR_ELEMS (25600 * 256)   // [50*512][256] f32 scratch (cur, then ff0 in place)
#define WROWS 65792               // 257 rows * 256 (row 256 = zeros for list padding)

// ---------------------------------------------------------------------------
// K0: one-time weight transposes into workspace (k-major for coalesced row
// gathers), each with an extra all-zero row at index 256 (list-padding sink).
// ---------------------------------------------------------------------------
__global__ __launch_bounds__(256) void k0_transpose(
    const float* __restrict__ Wf, const float* __restrict__ Wr,
    const float* __restrict__ Wo, float* __restrict__ ws) {
  int tid = blockIdx.x * blockDim.x + threadIdx.x;
  float* Wr0T = ws + CUR_ELEMS;
  float* Wf1T = Wr0T + WROWS;
  float* Wr1T = Wf1T + WROWS;
  float* WoT  = Wr1T + WROWS;
  if (tid < WROWS) {
    int k = tid >> 8, h = tid & 255;
    Wr0T[tid] = (k < 256) ? Wr[h * 256 + k] : 0.f;
  } else if (tid < 2 * WROWS) {
    int i = tid - WROWS; int k = i >> 8, h = i & 255;
    Wf1T[i] = (k < 256) ? Wf[65536 + h * 256 + k] : 0.f;
  } else if (tid < 3 * WROWS) {
    int i = tid - 2 * WROWS; int k = i >> 8, h = i & 255;
    Wr1T[i] = (k < 256) ? Wr[65536 + h * 256 + k] : 0.f;
  } else if (tid < 3 * WROWS + 5140) {
    int i = tid - 3 * WROWS; int k = i / 20, j = i - k * 20;
    WoT[i] = (k < 256) ? Wo[j * 256 + k] : 0.f;
  }
}

// ---------------------------------------------------------------------------
// K1: cur[t][b][h] = sum_i x[b, t-d_i, :] . Wd[i][h][:]  + sum_i bd[i][h]
// 128x128 tile, 8x8 micro-tile, double-buffered LDS, 2-ahead reg prefetch.
// EQUAL-COST SCHEDULE: 248 blocks x (3 or 4) passes. blockIdx -> up to 2
// output tiles (jobs); passes per tile run d-ascending exactly as before ->
// cur is BITWISE IDENTICAL to the 400-block version. Fours dispatch first.
//   u<6:   (t=32+u: 3 passes) + (t=u: 1)          [4 passes]
//   u<9:   (t=26+2e: 2) + (t=27+2e: 2), e=u-6     [4 passes]
//   u<21:  (t=38+(u-9): 3)                        [3 passes]
//   else:  (t=16+(u-21): 2) + (t=6+(u-21): 1)     [3 passes]
// ---------------------------------------------------------------------------
__global__ __launch_bounds__(256) void k1_cur(
    const float* __restrict__ x, const float* __restrict__ Wd,
    const float* __restrict__ bd, float* __restrict__ cur) {
  __shared__ float As[2][16][132];
  __shared__ float Bs[2][16][132];
  const int tile = blockIdx.x & 7;
  const int u = blockIdx.x >> 3;               // 0..30
  const int bt = tile >> 1, ht = tile & 1;
  const int b0 = bt * 128, h0 = ht * 128;
  const int tid = threadIdx.x;
  const int tx = tid & 15, ty = tid >> 4;
  const int r = tid & 127, half = tid >> 7;
  const int kk0a = half * 8;

  int tJ[2], nJ[2];
  if (u < 6)       { tJ[0] = 32 + u;          nJ[0] = 3; tJ[1] = u;              nJ[1] = 1; }
  else if (u < 9)  { tJ[0] = 26 + 2 * (u - 6); nJ[0] = 2; tJ[1] = 27 + 2 * (u - 6); nJ[1] = 2; }
  else if (u < 21) { tJ[0] = 38 + (u - 9);    nJ[0] = 3; tJ[1] = 0;              nJ[1] = 0; }
  else             { tJ[0] = 16 + (u - 21);   nJ[0] = 2; tJ[1] = 6 + (u - 21);   nJ[1] = 1; }

  float bias[8];
#pragma unroll
  for (int q = 0; q < 2; ++q)
#pragma unroll
    for (int c = 0; c < 4; ++c) {
      const int col = h0 + q * 64 + tx * 4 + c;
      bias[q * 4 + c] = bd[col] + bd[256 + col] + bd[512 + col];
    }

  const int DEL[3] = {0, 16, 32};
#pragma unroll 1
  for (int jb = 0; jb < 2; ++jb) {
    const int npass = nJ[jb];
    if (npass == 0) continue;
    const int t = tJ[jb];

    float acc[8][8];
#pragma unroll
    for (int i = 0; i < 8; ++i)
#pragma unroll
      for (int j = 0; j < 8; ++j) acc[i][j] = 0.f;

#pragma unroll 1
    for (int di = 0; di < npass; ++di) {
      const int tsrc = t - DEL[di];
      const float* Arow = x + ((size_t)(b0 + r) * 50 + tsrc) * 700;
      const float* Brow = Wd + (size_t)di * 179200 + (size_t)(h0 + r) * 700;
      float4 pa0, pa1, pb0, pb1;
      pa0 = *(const float4*)(Arow + kk0a);
      pa1 = *(const float4*)(Arow + kk0a + 4);
      pb0 = *(const float4*)(Brow + kk0a);
      pb1 = *(const float4*)(Brow + kk0a + 4);
      As[0][kk0a + 0][r] = pa0.x; As[0][kk0a + 1][r] = pa0.y;
      As[0][kk0a + 2][r] = pa0.z; As[0][kk0a + 3][r] = pa0.w;
      As[0][kk0a + 4][r] = pa1.x; As[0][kk0a + 5][r] = pa1.y;
      As[0][kk0a + 6][r] = pa1.z; As[0][kk0a + 7][r] = pa1.w;
      Bs[0][kk0a + 0][r] = pb0.x; Bs[0][kk0a + 1][r] = pb0.y;
      Bs[0][kk0a + 2][r] = pb0.z; Bs[0][kk0a + 3][r] = pb0.w;
      Bs[0][kk0a + 4][r] = pb1.x; Bs[0][kk0a + 5][r] = pb1.y;
      Bs[0][kk0a + 6][r] = pb1.z; Bs[0][kk0a + 7][r] = pb1.w;
      pa0 = *(const float4*)(Arow + 16 + kk0a);
      pa1 = *(const float4*)(Arow + 16 + kk0a + 4);
      pb0 = *(const float4*)(Brow + 16 + kk0a);
      pb1 = *(const float4*)(Brow + 16 + kk0a + 4);
      __syncthreads();
#pragma unroll 1
      for (int c = 0; c < 44; ++c) {
        const int cb = c & 1, nb = cb ^ 1;
        if (c < 43) {
          As[nb][kk0a + 0][r] = pa0.x; As[nb][kk0a + 1][r] = pa0.y;
          As[nb][kk0a + 2][r] = pa0.z; As[nb][kk0a + 3][r] = pa0.w;
          As[nb][kk0a + 4][r] = pa1.x; As[nb][kk0a + 5][r] = pa1.y;
          As[nb][kk0a + 6][r] = pa1.z; As[nb][kk0a + 7][r] = pa1.w;
          Bs[nb][kk0a + 0][r] = pb0.x; Bs[nb][kk0a + 1][r] = pb0.y;
          Bs[nb][kk0a + 2][r] = pb0.z; Bs[nb][kk0a + 3][r] = pb0.w;
          Bs[nb][kk0a + 4][r] = pb1.x; Bs[nb][kk0a + 5][r] = pb1.y;
          Bs[nb][kk0a + 6][r] = pb1.z; Bs[nb][kk0a + 7][r] = pb1.w;
        }
        if (c < 42) {
          const int i0 = (c + 2) * 16 + kk0a, i1 = i0 + 4;
          pa0 = (i0 + 3 < 700) ? *(const float4*)(Arow + i0)
                               : make_float4(0.f, 0.f, 0.f, 0.f);
          pa1 = (i1 + 3 < 700) ? *(const float4*)(Arow + i1)
                               : make_float4(0.f, 0.f, 0.f, 0.f);
          pb0 = (i0 + 3 < 700) ? *(const float4*)(Brow + i0)
                               : make_float4(0.f, 0.f, 0.f, 0.f);
          pb1 = (i1 + 3 < 700) ? *(const float4*)(Brow + i1)
                               : make_float4(0.f, 0.f, 0.f, 0.f);
        }
#pragma unroll
        for (int kk = 0; kk < 16; ++kk) {
          const float4 a0 = *(const float4*)&As[cb][kk][ty * 4];
          const float4 a1 = *(const float4*)&As[cb][kk][64 + ty * 4];
          const float4 c0 = *(const float4*)&Bs[cb][kk][tx * 4];
          const float4 c1 = *(const float4*)&Bs[cb][kk][64 + tx * 4];
          const float ar[8] = {a0.x, a0.y, a0.z, a0.w, a1.x, a1.y, a1.z, a1.w};
          const float br[8] = {c0.x, c0.y, c0.z, c0.w, c1.x, c1.y, c1.z, c1.w};
#pragma unroll
          for (int rr = 0; rr < 8; ++rr)
#pragma unroll
            for (int cc = 0; cc < 8; ++cc) acc[rr][cc] += ar[rr] * br[cc];
        }
        __syncthreads();
      }
    }
#pragma unroll
    for (int p = 0; p < 2; ++p)
#pragma unroll
      for (int rr = 0; rr < 4; ++rr) {
        const int row = b0 + p * 64 + ty * 4 + rr;
        float* dst = cur + ((size_t)t * 512 + row) * 256 + h0;
        const int ai = p * 4 + rr;
        float4 v0 = make_float4(acc[ai][0] + bias[0], acc[ai][1] + bias[1],
                                acc[ai][2] + bias[2], acc[ai][3] + bias[3]);
        float4 v1 = make_float4(acc[ai][4] + bias[4], acc[ai][5] + bias[5],
                                acc[ai][6] + bias[6], acc[ai][7] + bias[7]);
        *(float4*)(dst + tx * 4) = v0;
        *(float4*)(dst + 64 + tx * 4) = v1;
      }
    __syncthreads();   // all reads of LDS done before next job re-stages buf0
  }
}

// ---------------------------------------------------------------------------
// K1b: ff0[m][h] = cur[m][:] . Wf0[h][:] + bf0[h], IN PLACE over cur.
// ---------------------------------------------------------------------------
__global__ __launch_bounds__(256) void k1b_ff0(
    const float* __restrict__ Wf, const float* __restrict__ bf,
    float* __restrict__ cur) {
  __shared__ float As[16][68];
  __shared__ float Bs[16][260];
  const int m0 = blockIdx.x * 64;
  const int tid = threadIdx.x;
  const int tx = tid & 15, ty = tid >> 4;
  const int lr = tid & 63, akk = (tid >> 6) * 4;

  float acc[4][16];
#pragma unroll
  for (int i = 0; i < 4; ++i)
#pragma unroll
    for (int j = 0; j < 16; ++j) acc[i][j] = 0.f;

#pragma unroll 1
  for (int k0 = 0; k0 < 256; k0 += 16) {
    float4 av = *(const float4*)(cur + (size_t)(m0 + lr) * 256 + k0 + akk);
    As[akk + 0][lr] = av.x; As[akk + 1][lr] = av.y;
    As[akk + 2][lr] = av.z; As[akk + 3][lr] = av.w;
#pragma unroll
    for (int e = 0; e < 4; ++e) {
      const int hh = e * 64 + lr;
      float4 bv = *(const float4*)(Wf + (size_t)hh * 256 + k0 + akk);
      Bs[akk + 0][hh] = bv.x; Bs[akk + 1][hh] = bv.y;
      Bs[akk + 2][hh] = bv.z; Bs[akk + 3][hh] = bv.w;
    }
    __syncthreads();
#pragma unroll
    for (int kk = 0; kk < 16; ++kk) {
      const float4 a = *(const float4*)&As[kk][ty * 4];
      const float ar[4] = {a.x, a.y, a.z, a.w};
#pragma unroll
      for (int q = 0; q < 4; ++q) {
        const float4 bq = *(const float4*)&Bs[kk][q * 64 + tx * 4];
        const float br[4] = {bq.x, bq.y, bq.z, bq.w};
#pragma unroll
        for (int rr = 0; rr < 4; ++rr)
#pragma unroll
          for (int cc = 0; cc < 4; ++cc)
            acc[rr][q * 4 + cc] += ar[rr] * br[cc];
      }
    }
    __syncthreads();
  }
  float bias[16];
#pragma unroll
  for (int q = 0; q < 4; ++q)
#pragma unroll
    for (int c = 0; c < 4; ++c) bias[q * 4 + c] = bf[q * 64 + tx * 4 + c];
#pragma unroll
  for (int rr = 0; rr < 4; ++rr) {
    float* dst = cur + (size_t)(m0 + ty * 4 + rr) * 256;
#pragma unroll
    for (int q = 0; q < 4; ++q) {
      float4 v = make_float4(acc[rr][q * 4 + 0] + bias[q * 4 + 0],
                             acc[rr][q * 4 + 1] + bias[q * 4 + 1],
                             acc[rr][q * 4 + 2] + bias[q * 4 + 2],
                             acc[rr][q * 4 + 3] + bias[q * 4 + 3]);
      *(float4*)(dst + q * 64 + tx * 4) = v;
    }
  }
}

// ---------------------------------------------------------------------------
// K2 helpers (unchanged fp semantics). Lists: pre-scaled offsets (k<<8),
// %32-padded with the zero-row sink -> G is a multiple of 4.
// ---------------------------------------------------------------------------
__device__ __forceinline__ void load8rows(const float* __restrict__ W,
                                          const int* LC, int j, int l4,
                                          float4* w) {
  const int4 a = *(const int4*)(LC + j);
  const int4 c = *(const int4*)(LC + j + 4);
  w[0] = *(const float4*)(W + a.x + l4);
  w[1] = *(const float4*)(W + a.y + l4);
  w[2] = *(const float4*)(W + a.z + l4);
  w[3] = *(const float4*)(W + a.w + l4);
  w[4] = *(const float4*)(W + c.x + l4);
  w[5] = *(const float4*)(W + c.y + l4);
  w[6] = *(const float4*)(W + c.z + l4);
  w[7] = *(const float4*)(W + c.w + l4);
}

__device__ __forceinline__ void add8rows(float4& acc, const float4* w) {
  float4 t0, t1, t2, t3;
  t0.x = w[0].x + w[1].x; t0.y = w[0].y + w[1].y; t0.z = w[0].z + w[1].z; t0.w = w[0].w + w[1].w;
  t1.x = w[2].x + w[3].x; t1.y = w[2].y + w[3].y; t1.z = w[2].z + w[3].z; t1.w = w[2].w + w[3].w;
  t2.x = w[4].x + w[5].x; t2.y = w[4].y + w[5].y; t2.z = w[4].z + w[5].z; t2.w = w[4].w + w[5].w;
  t3.x = w[6].x + w[7].x; t3.y = w[6].y + w[7].y; t3.z = w[6].z + w[7].z; t3.w = w[6].w + w[7].w;
  t0.x += t1.x; t0.y += t1.y; t0.z += t1.z; t0.w += t1.w;
  t2.x += t3.x; t2.y += t3.y; t2.z += t3.z; t2.w += t3.w;
  acc.x += t0.x + t2.x; acc.y += t0.y + t2.y;
  acc.z += t0.z + t2.z; acc.w += t0.w + t2.w;
}

// Single-chain gather (used for the Wf1 pass): groups ascending, depth-4.
__device__ __forceinline__ float4 gather_rows(const float* __restrict__ W,
                                              const int* LC, int n, int l4) {
  float4 acc = make_float4(0.f, 0.f, 0.f, 0.f);
  const int G = n >> 3;
  if (G == 0) return acc;
  float4 w0[8], w1[8], w2[8], w3[8];
  load8rows(W, LC, 0,  l4, w0);
  load8rows(W, LC, 8,  l4, w1);
  load8rows(W, LC, 16, l4, w2);
  load8rows(W, LC, 24, l4, w3);
  int g = 4;
  for (; g + 4 <= G; g += 4) {
    add8rows(acc, w0); load8rows(W, LC, (g + 0) * 8, l4, w0);
    add8rows(acc, w1); load8rows(W, LC, (g + 1) * 8, l4, w1);
    add8rows(acc, w2); load8rows(W, LC, (g + 2) * 8, l4, w2);
    add8rows(acc, w3); load8rows(W, LC, (g + 3) * 8, l4, w3);
  }
  add8rows(acc, w0); add8rows(acc, w1);
  add8rows(acc, w2); add8rows(acc, w3);
  return acc;
}

// DUAL-chain gather: chain A (accA) and chain B (accB) interleaved group-by-
// group. Each chain adds its groups in ascending order -> each acc is
// BITWISE IDENTICAL to a solo gather over its list; the interleave only
// changes instruction scheduling (2 independent load->add chains in flight).
__device__ __forceinline__ void gather_dual(
    const float* __restrict__ WA, const int* LA, int nA,
    const float* __restrict__ WB, const int* LB, int nB, int l4,
    float4& accA, float4& accB) {
  const int GA = nA >> 3, GB = nB >> 3;   // multiples of 4
  float4 wa0[8], wa1[8], wb0[8], wb1[8];
  if (GA) { load8rows(WA, LA, 0, l4, wa0); load8rows(WA, LA, 8, l4, wa1); }
  if (GB) { load8rows(WB, LB, 0, l4, wb0); load8rows(WB, LB, 8, l4, wb1); }
  int ga = 0, gb = 0;
  while (ga + 4 <= GA && gb + 4 <= GB) {   // steady: alternate chains
    add8rows(accA, wa0); load8rows(WA, LA, (ga + 2) * 8, l4, wa0);
    add8rows(accB, wb0); load8rows(WB, LB, (gb + 2) * 8, l4, wb0);
    add8rows(accA, wa1); load8rows(WA, LA, (ga + 3) * 8, l4, wa1);
    add8rows(accB, wb1); load8rows(WB, LB, (gb + 3) * 8, l4, wb1);
    ga += 2; gb += 2;
  }
  if (GA) {
    while (ga + 4 <= GA) {                 // drain A solo (depth-2)
      add8rows(accA, wa0); load8rows(WA, LA, (ga + 2) * 8, l4, wa0);
      add8rows(accA, wa1); load8rows(WA, LA, (ga + 3) * 8, l4, wa1);
      ga += 2;
    }
    add8rows(accA, wa0); add8rows(accA, wa1);  // exactly 2 remain
  }
  if (GB) {
    while (gb + 4 <= GB) {                 // drain B solo
      add8rows(accB, wb0); load8rows(WB, LB, (gb + 2) * 8, l4, wb0);
      add8rows(accB, wb1); load8rows(WB, LB, (gb + 3) * 8, l4, wb1);
      gb += 2;
    }
    add8rows(accB, wb0); add8rows(accB, wb1);
  }
}

__device__ __forceinline__ float add8o(const float* w) {
  return ((w[0] + w[1]) + (w[2] + w[3])) + ((w[4] + w[5]) + (w[6] + w[7]));
}

// ---------------------------------------------------------------------------
// K2: 50-step recurrent scan. ONE WAVE per batch row (512 blocks x 64 thr),
// zero barriers. The Wr0T gather (layer 0, list spk0(t-1)) and the Wr1T
// gather (layer 1, list spk1(t-1)) are INDEPENDENT -> computed together via
// gather_dual at step start; gB is added exactly where R8 added g2, so all
// sums are bitwise identical to R8. Readout unchanged.
// ---------------------------------------------------------------------------
__global__ __launch_bounds__(64, 1) void k2_scan(
    const float* __restrict__ ff0, const float* __restrict__ Wr0T,
    const float* __restrict__ Wf1T, const float* __restrict__ Wr1T,
    const float* __restrict__ WoT, const float* __restrict__ bf,
    const float* __restrict__ bo, float* __restrict__ out) {
  __shared__ __align__(16) int LC0[288];   // spk0 offsets (k<<8), %32-padded
  __shared__ __align__(16) int LC1[288];   // spk1 offsets (k<<8), %32-padded
  __shared__ __align__(16) int LCb[280];   // spk1 offsets (k*20), %24-padded
  __shared__ float WoTl[5140];             // 257 x 20 (row 256 = zeros)
  __shared__ float obuf[20];
  const int b = blockIdx.x;
  const int lane = threadIdx.x;
  const int l4 = lane * 4;
  const unsigned long long lb = (1ull << lane) - 1ull;

  for (int i = lane; i < 1285; i += 64)
    *(float4*)(WoTl + 4 * i) = *(const float4*)(WoT + 4 * i);

  float4 m0 = make_float4(0.f, 0.f, 0.f, 0.f), m1 = m0;
  float4 s0v = m0, s1v = m0;
  const float4 bf1v = *(const float4*)(bf + 256 + l4);
  float omem = 0.f, ospk = 0.f, osum = 0.f, omot = 0.f;
  const float bov = (lane < 20) ? bo[lane] : 0.f;
  const int ro = lane / 3, rc = lane - ro * 3;   // readout map (lanes 0..59)
  int n0 = 0, n1g = 0, n1r = 0;

  const float* ffp = ff0 + (size_t)b * 256 + l4;
  float4 ff = *(const float4*)ffp;

#pragma unroll 1
  for (int t = 0; t < 50; ++t) {
    float4 ffn = ff;
    if (t < 49) ffn = *(const float4*)(ffp + (size_t)(t + 1) * 131072);
    // ---- dual gather: g0 = Wr0T over spk0(t-1); gB = Wr1T over spk1(t-1).
    // LC1/n1g are from step t-1 and not rewritten until later this step.
    float4 g0 = make_float4(0.f, 0.f, 0.f, 0.f);
    float4 gB = make_float4(0.f, 0.f, 0.f, 0.f);
    gather_dual(Wr0T, LC0, n0, Wr1T, LC1, n1g, l4, g0, gB);
    // ---- layer 0 membrane + spike
    {
      m0.x = m0.x * 0.8f * (1.f - s0v.x) + ff.x + g0.x;
      m0.y = m0.y * 0.8f * (1.f - s0v.y) + ff.y + g0.y;
      m0.z = m0.z * 0.8f * (1.f - s0v.z) + ff.z + g0.z;
      m0.w = m0.w * 0.8f * (1.f - s0v.w) + ff.w + g0.w;
      s0v.x = (m0.x - 0.3f > 0.f) ? 1.f : 0.f;
      s0v.y = (m0.y - 0.3f > 0.f) ? 1.f : 0.f;
      s0v.z = (m0.z - 0.3f > 0.f) ? 1.f : 0.f;
      s0v.w = (m0.w - 0.3f > 0.f) ? 1.f : 0.f;
    }
    {  // compact spk0 -> LC0 (%32-pad with zero-row sink)
      const float sv[4] = {s0v.x, s0v.y, s0v.z, s0v.w};
      int base = 0;
#pragma unroll
      for (int q = 0; q < 4; ++q) {
        const bool sp = sv[q] > 0.f;
        const unsigned long long mk = __ballot(sp);
        const int pos = base + (int)__popcll(mk & lb);
        if (sp) LC0[pos] = (l4 + q) << 8;
        base += (int)__popcll(mk);
      }
      const int pad = (-base) & 31;
      if (lane < pad) LC0[base + lane] = 256 << 8;
      n0 = base + pad;
    }
    // ---- layer 1: Wf1 gather over spk0(t); add gB exactly as R8's g2
    {
      const float4 g1 = gather_rows(Wf1T, LC0, n0, l4);
      m1.x = m1.x * 0.8f * (1.f - s1v.x) + bf1v.x + g1.x + gB.x;
      m1.y = m1.y * 0.8f * (1.f - s1v.y) + bf1v.y + g1.y + gB.y;
      m1.z = m1.z * 0.8f * (1.f - s1v.z) + bf1v.z + g1.z + gB.z;
      m1.w = m1.w * 0.8f * (1.f - s1v.w) + bf1v.w + g1.w + gB.w;
      s1v.x = (m1.x - 0.3f > 0.f) ? 1.f : 0.f;
      s1v.y = (m1.y - 0.3f > 0.f) ? 1.f : 0.f;
      s1v.z = (m1.z - 0.3f > 0.f) ? 1.f : 0.f;
      s1v.w = (m1.w - 0.3f > 0.f) ? 1.f : 0.f;
    }
    {  // compact spk1 -> LC1 (%32, k<<8) and LCb (%24, k*20)
      const float sv[4] = {s1v.x, s1v.y, s1v.z, s1v.w};
      int base = 0;
#pragma unroll
      for (int q = 0; q < 4; ++q) {
        const bool sp = sv[q] > 0.f;
        const unsigned long long mk = __ballot(sp);
        const int pos = base + (int)__popcll(mk & lb);
        if (sp) { LC1[pos] = (l4 + q) << 8; LCb[pos] = (l4 + q) * 20; }
        base += (int)__popcll(mk);
      }
      const int padg = (-base) & 31;
      if (lane < padg) LC1[base + lane] = 256 << 8;
      n1g = base + padg;
      const int rem = base % 24;
      const int padr = rem ? (24 - rem) : 0;
      if (lane < padr) LCb[base + lane] = 256 * 20;
      n1r = base + padr;
    }
    // ---- readout: lanes 0..59, 3 lanes per class, stride-3 LDS gather
    {
      float v = 0.f;
      if (lane < 60) {
        const int GR = n1r / 24;
        int j = rc;
        for (int g = 0; g < GR; ++g) {
          int idx[8]; float w[8];
#pragma unroll
          for (int u2 = 0; u2 < 8; ++u2) idx[u2] = LCb[j + 3 * u2];
#pragma unroll
          for (int u2 = 0; u2 < 8; ++u2) w[u2] = WoTl[idx[u2] + ro];
          v += add8o(w);
          j += 24;
        }
      }
      const float v1 = __shfl_down(v, 1);
      const float v2 = __shfl_down(v, 2);
      v += v1 + v2;
      if (rc == 0 && lane < 60) obuf[ro] = v;
      if (lane < 20) {
        const float oacc = bov + obuf[lane];
        omem = omem * 0.8f * (1.f - ospk) + oacc;
        ospk = (omem - 0.3f > 0.f) ? 1.f : 0.f;
        osum += ospk;
        obuf[lane] = omem;
      }
      if (lane < 20) {
        float ov[20];
#pragma unroll
        for (int j2 = 0; j2 < 20; ++j2) ov[j2] = obuf[j2];
        float mx = ov[0];
#pragma unroll
        for (int j2 = 1; j2 < 20; ++j2) mx = fmaxf(mx, ov[j2]);
        float sm = 0.f;
#pragma unroll
        for (int j2 = 0; j2 < 20; ++j2) sm += expf(ov[j2] - mx);
        omot += expf(omem - mx) / sm;
      }
    }
    ff = ffn;
  }
  if (lane < 20) {
    out[b * 20 + lane] = osum / 50.0f;
    out[10240 + b * 20 + lane] = omot;
  }
}

// ---------------------------------------------------------------------------
extern "C" void kernel_launch(void* const* d_in, const int* in_sizes, int n_in,
                              void* d_out, int out_size, void* d_ws, size_t ws_size,
                              hipStream_t stream) {
  const float* x  = (const float*)d_in[0];
  const float* Wd = (const float*)d_in[1];
  const float* bd = (const float*)d_in[2];
  const float* Wf = (const float*)d_in[3];
  const float* bf = (const float*)d_in[4];
  const float* Wr = (const float*)d_in[5];
  const float* Wo = (const float*)d_in[6];
  const float* bo = (const float*)d_in[7];
  float* out = (float*)d_out;
  float* ws  = (float*)d_ws;

  float* cur  = ws;                    // [25600][256], becomes ff0 in place
  float* Wr0T = ws + CUR_ELEMS;
  float* Wf1T = Wr0T + WROWS;
  float* Wr1T = Wf1T + WROWS;
  float* WoT  = Wr1T + WROWS;

  hipLaunchKernelGGL(k0_transpose, dim3(792), dim3(256), 0, stream, Wf, Wr, Wo, ws);
  hipLaunchKernelGGL(k1_cur, dim3(248), dim3(256), 0, stream, x, Wd, bd, cur);
  hipLaunchKernelGGL(k1b_ff0, dim3(400), dim3(256), 0, stream, Wf, bf, cur);
  hipLaunchKernelGGL(k2_scan, dim3(512), dim3(64), 0, stream, cur, Wr0T, Wf1T,
                     Wr1T, WoT, bf, bo, out);
}